// Round 1
// baseline (33390.195 us; speedup 1.0000x reference)
//
#include <hip/hip_runtime.h>
#include <math.h>

#define BATCH 8192
#define FEAT  64
#define HID   1024
#define NSTEPS 10

constexpr int BM = 64, BN = 64, BK = 16;

// MODE: 0 = plain C=A@B
//       1 = G1: C = tanh(acc + bias[n] + t*bias2[n])
//       2 = G2: h2 = tanh(acc + bias[n]) -> C; out2 = aux[m,n]*(1-h2^2)   (aux = g3)
//       3 = G3: C = acc + bias[n]
//       4 = G5: C = acc * (1 - aux[m,n]^2)                                 (aux = h1)
//       5 = G6: trace reduce: out2[m] = sum_n acc[m,n]*aux[m,n]            (aux = eps, N==64)
template<int MODE>
__global__ __launch_bounds__(256)
void gemm_k(const float* __restrict__ A, int lda,
            const float* __restrict__ B, int ldb,
            float* __restrict__ C,
            int M, int N, int K,
            const float* __restrict__ bias,
            const float* __restrict__ bias2, float tval,
            const float* __restrict__ aux,
            float* __restrict__ out2)
{
    __shared__ float As[BK][BM + 1];
    __shared__ float Bs[BK][BN + 1];
    const int tid  = threadIdx.x;
    const int trow = tid >> 4;   // 0..15
    const int tcol = tid & 15;   // 0..15
    const int m0 = blockIdx.y * BM;
    const int n0 = blockIdx.x * BN;

    float acc[4][4] = {};

    const int la_k = tid & 15;   // k within tile
    const int la_m = tid >> 4;   // row group base
    const int lb_n = tid & 63;
    const int lb_k = tid >> 6;   // 0..3

    for (int kt = 0; kt < K; kt += BK) {
#pragma unroll
        for (int i = 0; i < 4; i++) {
            As[la_k][la_m + 16 * i] =
                A[(size_t)(m0 + la_m + 16 * i) * lda + kt + la_k];
        }
#pragma unroll
        for (int i = 0; i < 4; i++) {
            Bs[lb_k + 4 * i][lb_n] =
                B[(size_t)(kt + lb_k + 4 * i) * ldb + n0 + lb_n];
        }
        __syncthreads();
#pragma unroll
        for (int k = 0; k < BK; k++) {
            float a[4], b[4];
#pragma unroll
            for (int i = 0; i < 4; i++) a[i] = As[k][trow * 4 + i];
#pragma unroll
            for (int j = 0; j < 4; j++) b[j] = Bs[k][tcol * 4 + j];
#pragma unroll
            for (int i = 0; i < 4; i++)
#pragma unroll
                for (int j = 0; j < 4; j++)
                    acc[i][j] += a[i] * b[j];
        }
        __syncthreads();
    }

    if (MODE == 5) {
        // fused trace reduction: out2[m] += over this block's 64 cols (grid.x==1)
        __shared__ float red[BM][17];
        float part[4];
#pragma unroll
        for (int i = 0; i < 4; i++) {
            int gm = m0 + trow * 4 + i;
            float s = 0.f;
#pragma unroll
            for (int j = 0; j < 4; j++) {
                int gn = n0 + tcol * 4 + j;
                s += acc[i][j] * aux[(size_t)gm * N + gn];
            }
            part[i] = s;
        }
#pragma unroll
        for (int i = 0; i < 4; i++) red[trow * 4 + i][tcol] = part[i];
        __syncthreads();
        if (tid < BM) {
            float s = 0.f;
#pragma unroll
            for (int c = 0; c < 16; c++) s += red[tid][c];
            out2[m0 + tid] = s;
        }
        return;
    }

#pragma unroll
    for (int i = 0; i < 4; i++) {
        int gm = m0 + trow * 4 + i;
#pragma unroll
        for (int j = 0; j < 4; j++) {
            int gn = n0 + tcol * 4 + j;
            size_t idx = (size_t)gm * (size_t)N + gn;
            float v = acc[i][j];
            if (MODE == 0) {
                C[idx] = v;
            } else if (MODE == 1) {
                C[idx] = tanhf(v + bias[gn] + tval * bias2[gn]);
            } else if (MODE == 2) {
                float hh = tanhf(v + bias[gn]);
                C[idx] = hh;
                out2[idx] = aux[idx] * (1.f - hh * hh);
            } else if (MODE == 3) {
                C[idx] = v + bias[gn];
            } else if (MODE == 4) {
                float hv = aux[idx];
                C[idx] = v * (1.f - hv * hv);
            }
        }
    }
}

__global__ void init_state(const float* __restrict__ x,
                           float* __restrict__ yx, float* __restrict__ yld)
{
    int i = blockIdx.x * 256 + threadIdx.x;
    if (i < BATCH * FEAT) yx[i] = x[i];
    if (i < BATCH) yld[i] = 0.f;
}

__global__ void transpose_w2(const float* __restrict__ in, float* __restrict__ out)
{
    __shared__ float tile[32][33];
    int bx = blockIdx.x * 32, by = blockIdx.y * 32;
    int tx = threadIdx.x, ty = threadIdx.y; // block (32,8)
    for (int i = 0; i < 32; i += 8)
        tile[ty + i][tx] = in[(size_t)(by + ty + i) * HID + bx + tx];
    __syncthreads();
    for (int i = 0; i < 32; i += 8)
        out[(size_t)(bx + ty + i) * HID + by + tx] = tile[tx][ty + i];
}

__global__ void make_w1xt(const float* __restrict__ W1, float* __restrict__ w1xt)
{
    int i = blockIdx.x * 256 + threadIdx.x; // HID*FEAT
    if (i < HID * FEAT) {
        int k = i / FEAT, n = i % FEAT;
        w1xt[i] = W1[(size_t)n * HID + k];
    }
}

__global__ void make_w3t(const float* __restrict__ W3, float* __restrict__ w3t)
{
    int i = blockIdx.x * 256 + threadIdx.x; // FEAT*HID
    if (i < FEAT * HID) {
        int k = i / HID, n = i % HID;
        w3t[i] = W3[(size_t)n * FEAT + k];
    }
}

// RK4 stage combine for x-part and logdet-part in one launch.
__global__ void rk4_combine(const float* __restrict__ yx, const float* __restrict__ yld,
                            const float* __restrict__ dx, const float* __restrict__ tr,
                            float* __restrict__ accx, float* __restrict__ accld,
                            float* __restrict__ ytmp,
                            float* __restrict__ yx_out, float* __restrict__ yld_out,
                            float wacc, float wtmp, int first, int fin, float h6)
{
    int i = blockIdx.x * 256 + threadIdx.x;
    if (i < BATCH * FEAT) {
        float d = dx[i];
        float a = (first ? 0.f : accx[i]) + wacc * d;
        accx[i] = a;
        if (fin) yx_out[i] = yx[i] + h6 * a;
        else     ytmp[i]   = yx[i] + wtmp * d;
    } else if (i < BATCH * FEAT + BATCH) {
        int m = i - BATCH * FEAT;
        float d = -tr[m];
        float a = (first ? 0.f : accld[m]) + wacc * d;
        accld[m] = a;
        if (fin) yld_out[m] = yld[m] + h6 * a;
    }
}

__global__ void write_out(const float* __restrict__ yx, const float* __restrict__ yld,
                          float* __restrict__ out)
{
    int i = blockIdx.x * 256 + threadIdx.x;
    if (i < BATCH * FEAT) out[i] = yx[i];
    else if (i < BATCH * FEAT + BATCH) out[i] = yld[i - BATCH * FEAT];
}

extern "C" void kernel_launch(void* const* d_in, const int* in_sizes, int n_in,
                              void* d_out, int out_size, void* d_ws, size_t ws_size,
                              hipStream_t stream)
{
    const float* x   = (const float*)d_in[0];
    const float* W1  = (const float*)d_in[1];
    const float* b1  = (const float*)d_in[2];
    const float* W2  = (const float*)d_in[3];
    const float* b2  = (const float*)d_in[4];
    const float* W3  = (const float*)d_in[5];
    const float* b3  = (const float*)d_in[6];
    const float* eps = (const float*)d_in[7];
    float* out = (float*)d_out;

    float* ws = (float*)d_ws;
    size_t o = 0;
    auto alloc = [&](size_t n) { float* p = ws + o; o += (n + 63) & ~(size_t)63; return p; };

    float* yx    = alloc((size_t)BATCH * FEAT);
    float* yld   = alloc(BATCH);
    float* ytmp  = alloc((size_t)BATCH * FEAT);
    float* accx  = alloc((size_t)BATCH * FEAT);
    float* accld = alloc(BATCH);
    float* dx    = alloc((size_t)BATCH * FEAT);
    float* tr    = alloc(BATCH);
    float* h1    = alloc((size_t)BATCH * HID);
    float* h2b   = alloc((size_t)BATCH * HID);
    float* g2    = alloc((size_t)BATCH * HID);
    float* g0    = alloc((size_t)BATCH * HID);
    float* g3    = alloc((size_t)BATCH * HID);
    float* w2t   = alloc((size_t)HID * HID);
    float* w1xt  = alloc((size_t)HID * FEAT);
    float* w3t   = alloc((size_t)FEAT * HID);

    dim3 blk(256);
    const dim3 gridBig(HID / BN, BATCH / BM);   // (16,128)
    const dim3 gridNarrow(FEAT / BN, BATCH / BM); // (1,128)
    const int combN = (BATCH * FEAT + BATCH + 255) / 256;

    // ---- setup (every call; deterministic) ----
    init_state<<<dim3((BATCH * FEAT + 255) / 256), blk, 0, stream>>>(x, yx, yld);
    transpose_w2<<<dim3(32, 32), dim3(32, 8), 0, stream>>>(W2, w2t);
    make_w1xt<<<dim3((HID * FEAT + 255) / 256), blk, 0, stream>>>(W1, w1xt);
    make_w3t<<<dim3((FEAT * HID + 255) / 256), blk, 0, stream>>>(W3, w3t);
    // g3 = eps @ W3^T  (constant across all evals)
    gemm_k<0><<<gridBig, blk, 0, stream>>>(eps, FEAT, w3t, HID, g3,
                                           BATCH, HID, FEAT,
                                           nullptr, nullptr, 0.f, nullptr, nullptr);

    const float h = 1.0f / NSTEPS;
    const float cs[4] = {0.f, 0.5f, 0.5f, 1.f};

    for (int s = 0; s < NSTEPS; s++) {
        float t0 = s * h;
        for (int st = 0; st < 4; st++) {
            const float* xin = (st == 0) ? yx : ytmp;
            float ts = t0 + cs[st] * h;
            // G1: h1 = tanh(xin @ W1[:64] + t*W1[64] + b1)
            gemm_k<1><<<gridBig, blk, 0, stream>>>(xin, FEAT, W1, HID, h1,
                                                   BATCH, HID, FEAT,
                                                   b1, W1 + (size_t)FEAT * HID, ts,
                                                   nullptr, nullptr);
            // G2: h2 = tanh(h1 @ W2 + b2); g2 = g3*(1-h2^2)
            gemm_k<2><<<gridBig, blk, 0, stream>>>(h1, HID, W2, HID, h2b,
                                                   BATCH, HID, HID,
                                                   b2, nullptr, 0.f, g3, g2);
            // G3: dx = h2 @ W3 + b3
            gemm_k<3><<<gridNarrow, blk, 0, stream>>>(h2b, HID, W3, FEAT, dx,
                                                      BATCH, FEAT, HID,
                                                      b3, nullptr, 0.f, nullptr, nullptr);
            // G5: g0 = (g2 @ W2^T) * (1 - h1^2)
            gemm_k<4><<<gridBig, blk, 0, stream>>>(g2, HID, w2t, HID, g0,
                                                   BATCH, HID, HID,
                                                   nullptr, nullptr, 0.f, h1, nullptr);
            // G6: tr[m] = sum_n (g0 @ W1[:64]^T)[m,n] * eps[m,n]
            gemm_k<5><<<gridNarrow, blk, 0, stream>>>(g0, HID, w1xt, FEAT, nullptr,
                                                      BATCH, FEAT, HID,
                                                      nullptr, nullptr, 0.f, eps, tr);
            // RK4 combine
            float wacc = (st == 1 || st == 2) ? 2.f : 1.f;
            float wtmp = (st == 0 || st == 1) ? h * 0.5f : h;
            rk4_combine<<<dim3(combN), blk, 0, stream>>>(yx, yld, dx, tr,
                                                         accx, accld, ytmp, yx, yld,
                                                         wacc, wtmp,
                                                         (st == 0) ? 1 : 0,
                                                         (st == 3) ? 1 : 0,
                                                         h / 6.f);
        }
    }

    write_out<<<dim3(combN), blk, 0, stream>>>(yx, yld, out);
}

// Round 2
// 4512.793 us; speedup vs baseline: 7.3990x; 7.3990x over previous
//
#include <hip/hip_runtime.h>
#include <math.h>

#define BATCH 8192
#define FEAT  64
#define HID   1024
#define NSTEPS 10

typedef __attribute__((ext_vector_type(8))) short bf16x8;
typedef __attribute__((ext_vector_type(4))) float f32x4;
typedef unsigned short u16;

__device__ __forceinline__ float bf2f(u16 u) {
    unsigned int v = ((unsigned int)u) << 16;
    return __builtin_bit_cast(float, v);
}
__device__ __forceinline__ u16 f2bf(float f) {
    unsigned int v = __builtin_bit_cast(unsigned int, f);
    v += 0x7FFFu + ((v >> 16) & 1u);
    return (u16)(v >> 16);
}

__device__ __forceinline__ void gload16(void* lds, const void* g) {
    __builtin_amdgcn_global_load_lds(
        (const __attribute__((address_space(1))) unsigned int*)g,
        (__attribute__((address_space(3))) unsigned int*)lds,
        16, 0, 0);
}

// A [M][K] bf16 row-major, Bt [N][K] bf16 row-major (i.e. B^T), fp32 accumulate.
// BM=128 fixed, 4 waves in 2x2, BK=32, global_load_lds staging.
// MODE 0: Cb = bf16(acc)                         (g3 precompute)
// MODE 1: Cb = bf16(tanh(acc + bias + t*bias2))  (G1 -> h1)
// MODE 2: h2=tanh(acc+bias)->Cb; Cb2=bf16(aux*(1-h2^2))  (G2 -> h2,g2; aux=g3)
// MODE 3: Cf partial (split-K, no bias)          (G3 -> dx partials)
// MODE 4: trace: trp[nblk][m] = sum_n acc*(1-aux^2)*Ef   (G5; aux=h1)
// MODE 5: Cf = acc                               (E precompute)
template<int MODE, int BN, int KCHUNK>
__global__ __launch_bounds__(256)
void mfma_gemm(const u16* __restrict__ A, int K,
               const u16* __restrict__ Bt, int N,
               float* __restrict__ Cf,
               u16* __restrict__ Cb,
               const float* __restrict__ bias,
               const float* __restrict__ bias2, float tval,
               const u16* __restrict__ auxb,
               const float* __restrict__ Ef,
               u16* __restrict__ Cb2,
               float* __restrict__ trp)
{
    constexpr int BM = 128;
    constexpr int FM = 4;          // BM / (2 waves * 16)
    constexpr int FN = BN / 32;    // BN / (2 waves * 16)

    __shared__ __align__(16) u16 As[BM * 32];
    __shared__ __align__(16) u16 Bs[BN * 32];

    const int tid  = threadIdx.x;
    const int wv   = tid >> 6;
    const int lane = tid & 63;
    const int l15  = lane & 15;
    const int l4   = lane >> 4;
    const int wr   = wv >> 1;
    const int wc   = wv & 1;

    const int m0 = blockIdx.y * BM;
    int n0, kb, ke;
    if constexpr (KCHUNK > 0) { n0 = 0; kb = blockIdx.x * KCHUNK; ke = kb + KCHUNK; }
    else                      { n0 = blockIdx.x * BN; kb = 0; ke = K; }

    f32x4 acc[FM][FN] = {};
    const int Lb = wv * 1024 + lane * 16;

    for (int kt = kb; kt < ke; kt += 32) {
#pragma unroll
        for (int q = 0; q < BM / 64; q++) {
            int L = q * 4096 + Lb;
            int row = L >> 6, colb = L & 63;
            gload16((char*)As + L,
                    (const char*)A + ((size_t)(m0 + row) * K + kt) * 2 + colb);
        }
#pragma unroll
        for (int q = 0; q < BN / 64; q++) {
            int L = q * 4096 + Lb;
            int row = L >> 6, colb = L & 63;
            gload16((char*)Bs + L,
                    (const char*)Bt + ((size_t)(n0 + row) * K + kt) * 2 + colb);
        }
        __syncthreads();

        bf16x8 af[FM], bfr[FN];
#pragma unroll
        for (int mi = 0; mi < FM; mi++) {
            int r = wr * (FM * 16) + mi * 16 + l15;
            af[mi] = *(const bf16x8*)&As[r * 32 + l4 * 8];
        }
#pragma unroll
        for (int nj = 0; nj < FN; nj++) {
            int c = wc * (FN * 16) + nj * 16 + l15;
            bfr[nj] = *(const bf16x8*)&Bs[c * 32 + l4 * 8];
        }
#pragma unroll
        for (int mi = 0; mi < FM; mi++)
#pragma unroll
            for (int nj = 0; nj < FN; nj++)
                acc[mi][nj] = __builtin_amdgcn_mfma_f32_16x16x32_bf16(
                    af[mi], bfr[nj], acc[mi][nj], 0, 0, 0);
        __syncthreads();
    }

    const int wmb = wr * (FM * 16);
    const int wnb = wc * (FN * 16);

    if constexpr (MODE == 4) {
        __shared__ float red[BM][32];
#pragma unroll
        for (int mi = 0; mi < FM; mi++) {
#pragma unroll
            for (int r = 0; r < 4; r++) {
                int lrow = wmb + mi * 16 + l4 * 4 + r;
                size_t gm = (size_t)(m0 + lrow);
                float s = 0.f;
#pragma unroll
                for (int nj = 0; nj < FN; nj++) {
                    int gn = n0 + wnb + nj * 16 + l15;
                    size_t idx = gm * (size_t)N + gn;
                    float h1v = bf2f(auxb[idx]);
                    float g0v = acc[mi][nj][r] * (1.f - h1v * h1v);
                    s += g0v * Ef[idx];
                }
                red[lrow][wc * 16 + l15] = s;
            }
        }
        __syncthreads();
        if (tid < BM) {
            float s = 0.f;
#pragma unroll
            for (int c = 0; c < 32; c++) s += red[tid][c];
            trp[(size_t)blockIdx.x * BATCH + m0 + tid] = s;
        }
        return;
    }

#pragma unroll
    for (int mi = 0; mi < FM; mi++) {
#pragma unroll
        for (int nj = 0; nj < FN; nj++) {
#pragma unroll
            for (int r = 0; r < 4; r++) {
                int gm = m0 + wmb + mi * 16 + l4 * 4 + r;
                int gn = n0 + wnb + nj * 16 + l15;
                float v = acc[mi][nj][r];
                if constexpr (MODE == 0) {
                    Cb[(size_t)gm * N + gn] = f2bf(v);
                } else if constexpr (MODE == 1) {
                    Cb[(size_t)gm * N + gn] = f2bf(tanhf(v + bias[gn] + tval * bias2[gn]));
                } else if constexpr (MODE == 2) {
                    size_t idx = (size_t)gm * N + gn;
                    float hh = tanhf(v + bias[gn]);
                    Cb[idx] = f2bf(hh);
                    float g3v = bf2f(auxb[idx]);
                    Cb2[idx] = f2bf(g3v * (1.f - hh * hh));
                } else if constexpr (MODE == 3) {
                    Cf[(size_t)blockIdx.x * (BATCH * 64) + (size_t)gm * 64 + gn] = v;
                } else if constexpr (MODE == 5) {
                    Cf[(size_t)gm * N + gn] = v;
                }
            }
        }
    }
}

__global__ void init_state(const float* __restrict__ x,
                           float* __restrict__ yx, u16* __restrict__ xin_bf,
                           float* __restrict__ yld)
{
    int i = blockIdx.x * 256 + threadIdx.x;
    if (i < BATCH * FEAT) { float v = x[i]; yx[i] = v; xin_bf[i] = f2bf(v); }
    if (i < BATCH) yld[i] = 0.f;
}

__global__ void cast_bf(const float* __restrict__ in, u16* __restrict__ out, int n)
{
    int i = blockIdx.x * 256 + threadIdx.x;
    if (i < n) out[i] = f2bf(in[i]);
}

// in [R][C] fp32 -> out [C][R] bf16
__global__ void transpose_cast(const float* __restrict__ in, u16* __restrict__ out,
                               int R, int C)
{
    __shared__ float t[32][33];
    int bx = blockIdx.x * 32, by = blockIdx.y * 32;
    int tx = threadIdx.x, ty = threadIdx.y;  // block (32,8)
    for (int i = 0; i < 32; i += 8)
        t[ty + i][tx] = in[(size_t)(by + ty + i) * C + bx + tx];
    __syncthreads();
    for (int i = 0; i < 32; i += 8)
        out[(size_t)(bx + ty + i) * R + by + tx] = f2bf(t[tx][ty + i]);
}

__global__ void rk4_combine(const float* __restrict__ part3, const float* __restrict__ b3,
                            const float* __restrict__ trpart,
                            float* __restrict__ yx, float* __restrict__ yld,
                            float* __restrict__ accx, float* __restrict__ accld,
                            float* __restrict__ ytmp, u16* __restrict__ xin_bf,
                            float wacc, float wtmp, int first, int fin, float h6)
{
    int i = blockIdx.x * 256 + threadIdx.x;
    if (i < BATCH * FEAT) {
        int f = i & 63;
        float d = b3[f];
#pragma unroll
        for (int kc = 0; kc < 8; kc++) d += part3[(size_t)kc * (BATCH * FEAT) + i];
        float a = (first ? 0.f : accx[i]) + wacc * d;
        accx[i] = a;
        float nx;
        if (fin) { nx = yx[i] + h6 * a; yx[i] = nx; }
        else     { nx = yx[i] + wtmp * d; ytmp[i] = nx; }
        xin_bf[i] = f2bf(nx);
    } else if (i < BATCH * FEAT + BATCH) {
        int m = i - BATCH * FEAT;
        float d = 0.f;
#pragma unroll
        for (int nb = 0; nb < 8; nb++) d += trpart[nb * BATCH + m];
        d = -d;
        float a = (first ? 0.f : accld[m]) + wacc * d;
        accld[m] = a;
        if (fin) yld[m] += h6 * a;
    }
}

__global__ void write_out(const float* __restrict__ yx, const float* __restrict__ yld,
                          float* __restrict__ out)
{
    int i = blockIdx.x * 256 + threadIdx.x;
    if (i < BATCH * FEAT) out[i] = yx[i];
    else if (i < BATCH * FEAT + BATCH) out[i] = yld[i - BATCH * FEAT];
}

extern "C" void kernel_launch(void* const* d_in, const int* in_sizes, int n_in,
                              void* d_out, int out_size, void* d_ws, size_t ws_size,
                              hipStream_t stream)
{
    const float* x   = (const float*)d_in[0];
    const float* W1  = (const float*)d_in[1];
    const float* b1  = (const float*)d_in[2];
    const float* W2  = (const float*)d_in[3];
    const float* b2  = (const float*)d_in[4];
    const float* W3  = (const float*)d_in[5];
    const float* b3  = (const float*)d_in[6];
    const float* eps = (const float*)d_in[7];
    float* out = (float*)d_out;

    char* ws = (char*)d_ws;
    size_t o = 0;
    auto alloc = [&](size_t bytes) { char* p = ws + o; o += (bytes + 255) & ~(size_t)255; return p; };

    float* yx     = (float*)alloc((size_t)BATCH * FEAT * 4);
    float* yld    = (float*)alloc(BATCH * 4);
    float* ytmp   = (float*)alloc((size_t)BATCH * FEAT * 4);
    float* accx   = (float*)alloc((size_t)BATCH * FEAT * 4);
    float* accld  = (float*)alloc(BATCH * 4);
    float* E      = (float*)alloc((size_t)BATCH * HID * 4);
    float* part3  = (float*)alloc((size_t)8 * BATCH * FEAT * 4);
    float* trpart = (float*)alloc((size_t)8 * BATCH * 4);
    u16* xin_bf   = (u16*)alloc((size_t)BATCH * FEAT * 2);
    u16* h1       = (u16*)alloc((size_t)BATCH * HID * 2);
    u16* h2       = (u16*)alloc((size_t)BATCH * HID * 2);
    u16* g2       = (u16*)alloc((size_t)BATCH * HID * 2);
    u16* g3       = (u16*)alloc((size_t)BATCH * HID * 2);
    u16* eps_bf   = (u16*)alloc((size_t)BATCH * FEAT * 2);
    u16* w1tb     = (u16*)alloc((size_t)HID * FEAT * 2);   // [1024][64] = W1[:64]^T
    u16* w2t_bf   = (u16*)alloc((size_t)HID * HID * 2);    // W2^T
    u16* w2_bf    = (u16*)alloc((size_t)HID * HID * 2);    // W2
    u16* w3t_bf   = (u16*)alloc((size_t)FEAT * HID * 2);   // [64][1024] = W3^T
    u16* w3_bf    = (u16*)alloc((size_t)HID * FEAT * 2);   // W3

    const dim3 blk(256);
    const dim3 gBig(HID / 128, BATCH / 128);   // (8, 64)
    const dim3 gK(8, BATCH / 128);             // split-K grid for G3
    const int combN = (BATCH * FEAT + BATCH + 255) / 256;

    // ---- setup (runs every call; deterministic) ----
    init_state<<<dim3((BATCH * FEAT + 255) / 256), blk, 0, stream>>>(x, yx, xin_bf, yld);
    cast_bf<<<dim3((HID * HID + 255) / 256), blk, 0, stream>>>(W2, w2_bf, HID * HID);
    cast_bf<<<dim3((HID * FEAT + 255) / 256), blk, 0, stream>>>(W3, w3_bf, HID * FEAT);
    cast_bf<<<dim3((BATCH * FEAT + 255) / 256), blk, 0, stream>>>(eps, eps_bf, BATCH * FEAT);
    transpose_cast<<<dim3(HID / 32, HID / 32), dim3(32, 8), 0, stream>>>(W2, w2t_bf, HID, HID);
    transpose_cast<<<dim3(HID / 32, FEAT / 32), dim3(32, 8), 0, stream>>>(W1, w1tb, FEAT, HID);
    transpose_cast<<<dim3(FEAT / 32, HID / 32), dim3(32, 8), 0, stream>>>(W3, w3t_bf, HID, FEAT);
    // g3 = eps @ W3^T   (Bt = W3 itself, [1024][64])
    mfma_gemm<0, 128, 0><<<gBig, blk, 0, stream>>>(eps_bf, FEAT, w3_bf, HID,
                                                   nullptr, g3, nullptr, nullptr, 0.f,
                                                   nullptr, nullptr, nullptr, nullptr);
    // E = eps @ W1[:64]  (Bt = w1tb [1024][64]) -> fp32
    mfma_gemm<5, 128, 0><<<gBig, blk, 0, stream>>>(eps_bf, FEAT, w1tb, HID,
                                                   E, nullptr, nullptr, nullptr, 0.f,
                                                   nullptr, nullptr, nullptr, nullptr);

    const float h = 1.0f / NSTEPS;
    const float cs[4] = {0.f, 0.5f, 0.5f, 1.f};

    for (int s = 0; s < NSTEPS; s++) {
        float t0 = s * h;
        for (int st = 0; st < 4; st++) {
            float ts = t0 + cs[st] * h;
            // G1: h1 = tanh(xin @ W1[:64] + t*W1[64] + b1)
            mfma_gemm<1, 128, 0><<<gBig, blk, 0, stream>>>(xin_bf, FEAT, w1tb, HID,
                                                           nullptr, h1, b1,
                                                           W1 + (size_t)FEAT * HID, ts,
                                                           nullptr, nullptr, nullptr, nullptr);
            // G2: h2 = tanh(h1 @ W2 + b2); g2 = g3*(1-h2^2)
            mfma_gemm<2, 128, 0><<<gBig, blk, 0, stream>>>(h1, HID, w2t_bf, HID,
                                                           nullptr, h2, b2, nullptr, 0.f,
                                                           g3, nullptr, g2, nullptr);
            // G3: dx partials = h2 @ W3 (split-K=8; bias added in combine)
            mfma_gemm<3, 64, 128><<<gK, blk, 0, stream>>>(h2, HID, w3t_bf, FEAT,
                                                          part3, nullptr, nullptr, nullptr, 0.f,
                                                          nullptr, nullptr, nullptr, nullptr);
            // G5+G6 fused: tr partials = sum_n (g2@W2^T)*(1-h1^2)*E
            mfma_gemm<4, 128, 0><<<gBig, blk, 0, stream>>>(g2, HID, w2_bf, HID,
                                                           nullptr, nullptr, nullptr, nullptr, 0.f,
                                                           h1, E, nullptr, trpart);
            // RK4 combine
            float wacc = (st == 1 || st == 2) ? 2.f : 1.f;
            float wtmp = (st == 0 || st == 1) ? h * 0.5f : h;
            rk4_combine<<<dim3(combN), blk, 0, stream>>>(part3, b3, trpart,
                                                         yx, yld, accx, accld,
                                                         ytmp, xin_bf,
                                                         wacc, wtmp,
                                                         (st == 0) ? 1 : 0,
                                                         (st == 3) ? 1 : 0,
                                                         h / 6.f);
        }
    }

    write_out<<<dim3(combN), blk, 0, stream>>>(yx, yld, out);
}

// Round 3
// 3334.563 us; speedup vs baseline: 10.0134x; 1.3533x over previous
//
#include <hip/hip_runtime.h>
#include <math.h>

#define BATCH 8192
#define FEAT  64
#define HID   1024
#define NSTEPS 10
#define SPLITK 4

typedef __attribute__((ext_vector_type(8))) short bf16x8;
typedef __attribute__((ext_vector_type(4))) float f32x4;
typedef unsigned short u16;

__device__ __forceinline__ float bf2f(u16 u) {
    unsigned int v = ((unsigned int)u) << 16;
    return __builtin_bit_cast(float, v);
}
__device__ __forceinline__ u16 f2bf(float f) {
    unsigned int v = __builtin_bit_cast(unsigned int, f);
    v += 0x7FFFu + ((v >> 16) & 1u);
    return (u16)(v >> 16);
}
// storage swizzle: 16B slot s of row m -> s ^ (m&3) ^ ((m>>2)&3). Applied by
// ALL producers of GEMM A/B tensors and by fragment ds_reads; global_load_lds
// copies 64B segments verbatim so staging needs no per-lane swizzle (rule 21).
__device__ __forceinline__ int swzv(int m) { return (m & 3) ^ ((m >> 2) & 3); }
__device__ __forceinline__ size_t swz_off(int m, int k, int K) {
    int s = ((k >> 3) & 3) ^ swzv(m);
    return (size_t)m * K + (k & ~31) + (s << 3) + (k & 7);
}
__device__ __forceinline__ float tanh_fast(float x) {
    x = fminf(20.f, fmaxf(-20.f, x));
    float e = __builtin_amdgcn_exp2f(x * 2.8853900817779268f); // e^(2x)
    return 1.f - 2.f * __builtin_amdgcn_rcpf(e + 1.f);
}
__device__ __forceinline__ void gload16(void* lds, const void* g) {
    __builtin_amdgcn_global_load_lds(
        (const __attribute__((address_space(1))) unsigned int*)g,
        (__attribute__((address_space(3))) unsigned int*)lds,
        16, 0, 0);
}

// A [M][K] bf16 swizzled, Bt [N][K] bf16 swizzled (B^T layout), fp32 acc.
// BM=128, 4 waves 2x2, BK=32, double-buffered global_load_lds, 2-phase.
// MODE 0: Cb = bf16(acc)                          (g3 / E precompute)
// MODE 1: Cb = bf16(tanh(acc+bias+t*bias2))       (G1 -> h1)
// MODE 2: h2=tanh(acc+bias)->Cb; Cb2=aux*(1-h2^2) (G2 -> h2,g2; aux=g3)
// MODE 3: Cf split-K partial, no epilogue fusion  (G3 -> dx partials)
// MODE 4: trp[blk][m] = sum_n acc*(1-aux^2)*E     (G5+trace; aux=h1)
template<int MODE, int BN, int KCHUNK>
__global__ __launch_bounds__(256)
void mfma_gemm(const u16* __restrict__ A, int K,
               const u16* __restrict__ Bt, int N,
               float* __restrict__ Cf, u16* __restrict__ Cb,
               const float* __restrict__ bias, const float* __restrict__ bias2,
               float tval,
               const u16* __restrict__ auxb, const u16* __restrict__ Eb,
               u16* __restrict__ Cb2, float* __restrict__ trp)
{
    constexpr int BM = 128;
    constexpr int FM = 4;
    constexpr int FN = BN / 32;
    constexpr int ABYTES = BM * 32 * 2;   // 8 KiB
    constexpr int BBYTES = BN * 32 * 2;
    __shared__ __align__(16) char smem[2 * (ABYTES + BBYTES)];

    const int tid  = threadIdx.x;
    const int wv   = tid >> 6, lane = tid & 63;
    const int l15  = lane & 15, l4 = lane >> 4;
    const int wr   = wv >> 1, wc = wv & 1;
    const int sxe  = ((l15 & 3) ^ ((l15 >> 2) & 3)) << 3;  // fragment slot XOR (elems)

    const int m0 = blockIdx.y * BM;
    int n0, kb;
    if constexpr (KCHUNK > 0) { n0 = 0; kb = blockIdx.x * KCHUNK; }
    else                      { n0 = blockIdx.x * BN; kb = 0; }
    const int ntiles = (KCHUNK > 0) ? (KCHUNK / 32) : (K / 32);

    const int Lb = wv * 1024 + lane * 16;

    auto stage = [&](int buf, int kt) {
        char* Asb = smem + buf * ABYTES;
        char* Bsb = smem + 2 * ABYTES + buf * BBYTES;
#pragma unroll
        for (int q = 0; q < BM / 64; q++) {
            int L = q * 4096 + Lb;
            int row = L >> 6, colb = L & 63;
            gload16(Asb + L, (const char*)A + ((size_t)(m0 + row) * K + kt) * 2 + colb);
        }
#pragma unroll
        for (int q = 0; q < BN / 64; q++) {
            int L = q * 4096 + Lb;
            int row = L >> 6, colb = L & 63;
            gload16(Bsb + L, (const char*)Bt + ((size_t)(n0 + row) * K + kt) * 2 + colb);
        }
    };

    f32x4 acc[FM][FN] = {};
    stage(0, kb);
    __syncthreads();
    int buf = 0;
    for (int t = 0; t < ntiles; t++) {
        if (t + 1 < ntiles) stage(buf ^ 1, kb + (t + 1) * 32);  // prefetch in flight
        const u16* Asb = (const u16*)(smem + buf * ABYTES);
        const u16* Bsb = (const u16*)(smem + 2 * ABYTES + buf * BBYTES);
        bf16x8 af[FM], bfr[FN];
#pragma unroll
        for (int mi = 0; mi < FM; mi++) {
            int r = wr * 64 + mi * 16 + l15;
            af[mi] = *(const bf16x8*)&Asb[r * 32 + ((l4 << 3) ^ sxe)];
        }
#pragma unroll
        for (int nj = 0; nj < FN; nj++) {
            int c = wc * (FN * 16) + nj * 16 + l15;
            bfr[nj] = *(const bf16x8*)&Bsb[c * 32 + ((l4 << 3) ^ sxe)];
        }
#pragma unroll
        for (int mi = 0; mi < FM; mi++)
#pragma unroll
            for (int nj = 0; nj < FN; nj++)
                acc[mi][nj] = __builtin_amdgcn_mfma_f32_16x16x32_bf16(
                    af[mi], bfr[nj], acc[mi][nj], 0, 0, 0);
        __syncthreads();
        buf ^= 1;
    }

    if constexpr (MODE == 3) {
#pragma unroll
        for (int mi = 0; mi < FM; mi++)
#pragma unroll
            for (int nj = 0; nj < FN; nj++)
#pragma unroll
                for (int r = 0; r < 4; r++) {
                    int gm = m0 + wr * 64 + mi * 16 + l4 * 4 + r;
                    int gn = n0 + wc * (FN * 16) + nj * 16 + l15;
                    Cf[(size_t)blockIdx.x * (BATCH * 64) + (size_t)gm * 64 + gn]
                        = acc[mi][nj][r];
                }
        return;
    }

    // ---- LDS-roundtrip epilogue: acc -> ep chunk -> vectorized global ----
    float* ep  = (float*)smem;              // [128][34]
    float* red = (float*)(smem + 17408);    // [128][2]  (MODE 4)
    const int erow = tid >> 1, ehalf = tid & 1;
    const int esw  = swzv(erow);
    float tsum = 0.f;
#pragma unroll
    for (int c = 0; c < BN / 32; c++) {
        __syncthreads();
        if (wc == (c >> 1)) {
            int njb = (c & 1) * 2;
#pragma unroll
            for (int mi = 0; mi < FM; mi++)
#pragma unroll
                for (int jj = 0; jj < 2; jj++)
#pragma unroll
                    for (int r = 0; r < 4; r++) {
                        int row = wr * 64 + mi * 16 + l4 * 4 + r;
                        ep[row * 34 + jj * 16 + l15] = acc[mi][njb + jj][r];
                    }
        }
        __syncthreads();
        float v[16];
#pragma unroll
        for (int j = 0; j < 16; j++) v[j] = ep[erow * 34 + ehalf * 16 + j];
        const int gm = m0 + erow;
        const int kcb = n0 + c * 32;
        const int kbase = kcb + ehalf * 16;
        const int g0 = ehalf * 2;
        const size_t rowoff = (size_t)gm * N + kcb;
        const size_t idxA = rowoff + (size_t)(((g0    ) ^ esw) << 3);
        const size_t idxB = rowoff + (size_t)(((g0 + 1) ^ esw) << 3);

        if constexpr (MODE == 0) {
            union { bf16x8 v8; u16 u[8]; } pa, pb;
#pragma unroll
            for (int j = 0; j < 8; j++) { pa.u[j] = f2bf(v[j]); pb.u[j] = f2bf(v[j + 8]); }
            *(bf16x8*)(Cb + idxA) = pa.v8;
            *(bf16x8*)(Cb + idxB) = pb.v8;
        } else if constexpr (MODE == 1) {
            union { bf16x8 v8; u16 u[8]; } pa, pb;
#pragma unroll
            for (int j = 0; j < 8; j++) {
                pa.u[j] = f2bf(tanh_fast(v[j] + bias[kbase + j] + tval * bias2[kbase + j]));
                pb.u[j] = f2bf(tanh_fast(v[j + 8] + bias[kbase + 8 + j] + tval * bias2[kbase + 8 + j]));
            }
            *(bf16x8*)(Cb + idxA) = pa.v8;
            *(bf16x8*)(Cb + idxB) = pb.v8;
        } else if constexpr (MODE == 2) {
            union { bf16x8 v8; u16 u[8]; } ha, hb, ga, gb;
            bf16x8 a0 = *(const bf16x8*)(auxb + idxA);
            bf16x8 a1 = *(const bf16x8*)(auxb + idxB);
#pragma unroll
            for (int j = 0; j < 8; j++) {
                float h0 = tanh_fast(v[j] + bias[kbase + j]);
                float h1v = tanh_fast(v[j + 8] + bias[kbase + 8 + j]);
                ha.u[j] = f2bf(h0);
                hb.u[j] = f2bf(h1v);
                ga.u[j] = f2bf(bf2f((u16)a0[j]) * (1.f - h0 * h0));
                gb.u[j] = f2bf(bf2f((u16)a1[j]) * (1.f - h1v * h1v));
            }
            *(bf16x8*)(Cb  + idxA) = ha.v8;
            *(bf16x8*)(Cb  + idxB) = hb.v8;
            *(bf16x8*)(Cb2 + idxA) = ga.v8;
            *(bf16x8*)(Cb2 + idxB) = gb.v8;
        } else if constexpr (MODE == 4) {
            bf16x8 a0 = *(const bf16x8*)(auxb + idxA);
            bf16x8 a1 = *(const bf16x8*)(auxb + idxB);
            bf16x8 e0 = *(const bf16x8*)(Eb + idxA);
            bf16x8 e1 = *(const bf16x8*)(Eb + idxB);
#pragma unroll
            for (int j = 0; j < 8; j++) {
                float h0 = bf2f((u16)a0[j]), h1v = bf2f((u16)a1[j]);
                tsum += v[j]     * (1.f - h0 * h0)   * bf2f((u16)e0[j]);
                tsum += v[j + 8] * (1.f - h1v * h1v) * bf2f((u16)e1[j]);
            }
        }
    }
    if constexpr (MODE == 4) {
        red[erow * 2 + ehalf] = tsum;
        __syncthreads();
        if (tid < BM)
            trp[(size_t)blockIdx.x * BATCH + m0 + tid] = red[tid * 2] + red[tid * 2 + 1];
    }
}

__global__ void init_state(const float* __restrict__ x,
                           float* __restrict__ yx, u16* __restrict__ xin_bf,
                           float* __restrict__ yld)
{
    int i = blockIdx.x * 256 + threadIdx.x;
    if (i < BATCH * FEAT) {
        float v = x[i];
        yx[i] = v;
        xin_bf[swz_off(i >> 6, i & 63, 64)] = f2bf(v);
    }
    if (i < BATCH) yld[i] = 0.f;
}

__global__ void cast_bf(const float* __restrict__ in, u16* __restrict__ out,
                        int n, int W)
{
    int i = blockIdx.x * 256 + threadIdx.x;
    if (i < n) out[swz_off(i / W, i % W, W)] = f2bf(in[i]);
}

// in [R][C] fp32 -> out [C][R] bf16 swizzled
__global__ void transpose_cast(const float* __restrict__ in, u16* __restrict__ out,
                               int R, int C)
{
    __shared__ float t[32][33];
    int bx = blockIdx.x * 32, by = blockIdx.y * 32;
    int tx = threadIdx.x, ty = threadIdx.y;  // block (32,8)
    for (int i = 0; i < 32; i += 8)
        t[ty + i][tx] = in[(size_t)(by + ty + i) * C + bx + tx];
    __syncthreads();
    for (int i = 0; i < 32; i += 8)
        out[swz_off(bx + ty + i, by + tx, R)] = f2bf(t[tx][ty + i]);
}

__global__ void rk4_combine(const float* __restrict__ part3, const float* __restrict__ b3,
                            const float* __restrict__ trpart,
                            float* __restrict__ yx, float* __restrict__ yld,
                            float* __restrict__ accx, float* __restrict__ accld,
                            float* __restrict__ ytmp, u16* __restrict__ xin_bf,
                            float wacc, float wtmp, int first, int fin, float h6)
{
    int i = blockIdx.x * 256 + threadIdx.x;
    if (i < BATCH * FEAT) {
        int f = i & 63;
        float d = b3[f];
#pragma unroll
        for (int kc = 0; kc < SPLITK; kc++) d += part3[(size_t)kc * (BATCH * FEAT) + i];
        float a = (first ? 0.f : accx[i]) + wacc * d;
        accx[i] = a;
        float nx;
        if (fin) { nx = yx[i] + h6 * a; yx[i] = nx; }
        else     { nx = yx[i] + wtmp * d; ytmp[i] = nx; }
        xin_bf[swz_off(i >> 6, f, 64)] = f2bf(nx);
    } else if (i < BATCH * FEAT + BATCH) {
        int m = i - BATCH * FEAT;
        float d = 0.f;
#pragma unroll
        for (int nb = 0; nb < 8; nb++) d += trpart[nb * BATCH + m];
        d = -d;
        float a = (first ? 0.f : accld[m]) + wacc * d;
        accld[m] = a;
        if (fin) yld[m] += h6 * a;
    }
}

__global__ void write_out(const float* __restrict__ yx, const float* __restrict__ yld,
                          float* __restrict__ out)
{
    int i = blockIdx.x * 256 + threadIdx.x;
    if (i < BATCH * FEAT) out[i] = yx[i];
    else if (i < BATCH * FEAT + BATCH) out[i] = yld[i - BATCH * FEAT];
}

extern "C" void kernel_launch(void* const* d_in, const int* in_sizes, int n_in,
                              void* d_out, int out_size, void* d_ws, size_t ws_size,
                              hipStream_t stream)
{
    const float* x   = (const float*)d_in[0];
    const float* W1  = (const float*)d_in[1];
    const float* b1  = (const float*)d_in[2];
    const float* W2  = (const float*)d_in[3];
    const float* b2  = (const float*)d_in[4];
    const float* W3  = (const float*)d_in[5];
    const float* b3  = (const float*)d_in[6];
    const float* eps = (const float*)d_in[7];
    float* out = (float*)d_out;

    char* ws = (char*)d_ws;
    size_t o = 0;
    auto alloc = [&](size_t bytes) { char* p = ws + o; o += (bytes + 255) & ~(size_t)255; return p; };

    float* yx     = (float*)alloc((size_t)BATCH * FEAT * 4);
    float* yld    = (float*)alloc(BATCH * 4);
    float* ytmp   = (float*)alloc((size_t)BATCH * FEAT * 4);
    float* accx   = (float*)alloc((size_t)BATCH * FEAT * 4);
    float* accld  = (float*)alloc(BATCH * 4);
    float* part3  = (float*)alloc((size_t)SPLITK * BATCH * FEAT * 4);
    float* trpart = (float*)alloc((size_t)8 * BATCH * 4);
    u16* xin_bf   = (u16*)alloc((size_t)BATCH * FEAT * 2);
    u16* h1       = (u16*)alloc((size_t)BATCH * HID * 2);
    u16* h2       = (u16*)alloc((size_t)BATCH * HID * 2);
    u16* g2       = (u16*)alloc((size_t)BATCH * HID * 2);
    u16* g3       = (u16*)alloc((size_t)BATCH * HID * 2);
    u16* E_bf     = (u16*)alloc((size_t)BATCH * HID * 2);
    u16* eps_bf   = (u16*)alloc((size_t)BATCH * FEAT * 2);
    u16* w1tb     = (u16*)alloc((size_t)HID * FEAT * 2);   // [1024][64] = W1[:64]^T
    u16* w2t_bf   = (u16*)alloc((size_t)HID * HID * 2);    // W2^T
    u16* w2_bf    = (u16*)alloc((size_t)HID * HID * 2);    // W2
    u16* w3t_bf   = (u16*)alloc((size_t)FEAT * HID * 2);   // [64][1024] = W3^T
    u16* w3_bf    = (u16*)alloc((size_t)HID * FEAT * 2);   // W3

    const dim3 blk(256);
    const dim3 gBig(HID / 128, BATCH / 128);   // (8, 64)
    const dim3 gK(SPLITK, BATCH / 128);        // (4, 64)
    const int combN = (BATCH * FEAT + BATCH + 255) / 256;

    // ---- setup (every call; deterministic) ----
    init_state<<<dim3((BATCH * FEAT + 255) / 256), blk, 0, stream>>>(x, yx, xin_bf, yld);
    cast_bf<<<dim3((HID * HID + 255) / 256), blk, 0, stream>>>(W2, w2_bf, HID * HID, HID);
    cast_bf<<<dim3((HID * FEAT + 255) / 256), blk, 0, stream>>>(W3, w3_bf, HID * FEAT, FEAT);
    cast_bf<<<dim3((BATCH * FEAT + 255) / 256), blk, 0, stream>>>(eps, eps_bf, BATCH * FEAT, FEAT);
    transpose_cast<<<dim3(HID / 32, HID / 32), dim3(32, 8), 0, stream>>>(W2, w2t_bf, HID, HID);
    transpose_cast<<<dim3(HID / 32, FEAT / 32), dim3(32, 8), 0, stream>>>(W1, w1tb, FEAT, HID);
    transpose_cast<<<dim3(FEAT / 32, HID / 32), dim3(32, 8), 0, stream>>>(W3, w3t_bf, HID, FEAT);
    // g3 = eps @ W3^T
    mfma_gemm<0, 128, 0><<<gBig, blk, 0, stream>>>(eps_bf, FEAT, w3_bf, HID,
                                                   nullptr, g3, nullptr, nullptr, 0.f,
                                                   nullptr, nullptr, nullptr, nullptr);
    // E = eps @ W1[:64]   (bf16)
    mfma_gemm<0, 128, 0><<<gBig, blk, 0, stream>>>(eps_bf, FEAT, w1tb, HID,
                                                   nullptr, E_bf, nullptr, nullptr, 0.f,
                                                   nullptr, nullptr, nullptr, nullptr);

    const float h = 1.0f / NSTEPS;
    const float cs[4] = {0.f, 0.5f, 0.5f, 1.f};

    for (int s = 0; s < NSTEPS; s++) {
        float t0 = s * h;
        for (int st = 0; st < 4; st++) {
            float ts = t0 + cs[st] * h;
            // G1: h1 = tanh(xin @ W1[:64] + t*W1[64] + b1)
            mfma_gemm<1, 128, 0><<<gBig, blk, 0, stream>>>(xin_bf, FEAT, w1tb, HID,
                                                           nullptr, h1, b1,
                                                           W1 + (size_t)FEAT * HID, ts,
                                                           nullptr, nullptr, nullptr, nullptr);
            // G2: h2 = tanh(h1 @ W2 + b2); g2 = g3*(1-h2^2)
            mfma_gemm<2, 128, 0><<<gBig, blk, 0, stream>>>(h1, HID, w2t_bf, HID,
                                                           nullptr, h2, b2, nullptr, 0.f,
                                                           g3, nullptr, g2, nullptr);
            // G3: dx partials = h2 @ W3 (split-K=4; bias in combine)
            mfma_gemm<3, 64, HID / SPLITK><<<gK, blk, 0, stream>>>(h2, HID, w3t_bf, FEAT,
                                                          part3, nullptr, nullptr, nullptr, 0.f,
                                                          nullptr, nullptr, nullptr, nullptr);
            // G5+trace: trpart = rowsum( (g2@W2^T) * (1-h1^2) * E )
            mfma_gemm<4, 128, 0><<<gBig, blk, 0, stream>>>(g2, HID, w2_bf, HID,
                                                           nullptr, nullptr, nullptr, nullptr, 0.f,
                                                           h1, E_bf, nullptr, trpart);
            float wacc = (st == 1 || st == 2) ? 2.f : 1.f;
            float wtmp = (st == 0 || st == 1) ? h * 0.5f : h;
            rk4_combine<<<dim3(combN), blk, 0, stream>>>(part3, b3, trpart,
                                                         yx, yld, accx, accld,
                                                         ytmp, xin_bf,
                                                         wacc, wtmp,
                                                         (st == 0) ? 1 : 0,
                                                         (st == 3) ? 1 : 0,
                                                         h / 6.f);
        }
    }

    write_out<<<dim3(combN), blk, 0, stream>>>(yx, yld, out);
}

// Round 4
// 2714.561 us; speedup vs baseline: 12.3004x; 1.2284x over previous
//
#include <hip/hip_runtime.h>
#include <math.h>

#define BATCH 8192
#define FEAT  64
#define HID   1024
#define NSTEPS 8
#define SPLITK 4

typedef __attribute__((ext_vector_type(8))) short bf16x8;
typedef __attribute__((ext_vector_type(4))) float f32x4;
typedef unsigned short u16;

__device__ __forceinline__ float bf2f(u16 u) {
    unsigned int v = ((unsigned int)u) << 16;
    return __builtin_bit_cast(float, v);
}
__device__ __forceinline__ u16 f2bf(float f) {
    unsigned int v = __builtin_bit_cast(unsigned int, f);
    v += 0x7FFFu + ((v >> 16) & 1u);
    return (u16)(v >> 16);
}
// storage swizzle: within each 128B (64-elem) window of row m, 16B slot s -> s^(m&7).
// Producers write swizzled global; global_load_lds copies 128B row-windows verbatim
// (rule 21: swizzle lives in producer writes + swz-aware ds_read / epilogue reads).
__device__ __forceinline__ size_t swz_off(int m, int k, int K) {
    int s = (k >> 3) & 7;
    return (size_t)m * K + (k & ~63) + ((s ^ (m & 7)) << 3) + (k & 7);
}
// 16B-slot-granular address (gs = global slot index = col/8)
__device__ __forceinline__ size_t swz_slot(int m, int gs, int N) {
    return (size_t)m * N + (((gs & ~7) | ((gs & 7) ^ (m & 7))) << 3);
}
__device__ __forceinline__ float tanh_fast(float x) {
    x = fminf(20.f, fmaxf(-20.f, x));
    float e = __builtin_amdgcn_exp2f(x * 2.8853900817779268f); // e^(2x)
    return 1.f - 2.f * __builtin_amdgcn_rcpf(e + 1.f);
}
__device__ __forceinline__ void gload16(void* lds, const void* g) {
    __builtin_amdgcn_global_load_lds(
        (const __attribute__((address_space(1))) unsigned int*)g,
        (__attribute__((address_space(3))) unsigned int*)lds,
        16, 0, 0);
}

// Shared K-loop: A [M][K] bf16 swizzled, Bt [N][K] bf16 swizzled, BM=128, BK=64,
// 4 waves 2x2, double-buffered global_load_lds, 2-phase prefetch.
// smem layout: A bufs at 0 / 16384; B bufs at 32768 / 32768+BN*128.
template<int BN>
__device__ __forceinline__ void kloop(const u16* __restrict__ A,
                                      const u16* __restrict__ Bt,
                                      int K, int m0, int n0, int kb, int ntiles,
                                      char* __restrict__ smem,
                                      f32x4 (&acc)[4][BN / 32])
{
    constexpr int FN = BN / 32;
    const int tid = threadIdx.x, wv = tid >> 6, lane = tid & 63;
    const int l15 = lane & 15, l4 = lane >> 4;
    const int wr = wv >> 1, wc = wv & 1;
    const int Lb = tid * 16;

    auto stage = [&](int buf, int kt) {
        char* Asb = smem + buf * 16384;
        char* Bsb = smem + 32768 + buf * (BN * 128);
#pragma unroll
        for (int q = 0; q < 4; q++) {
            int L = q * 4096 + Lb;
            int row = L >> 7, colb = L & 127;
            gload16(Asb + L, (const char*)A + ((size_t)(m0 + row) * K + kt) * 2 + colb);
        }
#pragma unroll
        for (int q = 0; q < BN / 32; q++) {
            int L = q * 4096 + Lb;
            int row = L >> 7, colb = L & 127;
            gload16(Bsb + L, (const char*)Bt + ((size_t)(n0 + row) * K + kt) * 2 + colb);
        }
    };

    stage(0, kb);
    __syncthreads();
    int buf = 0;
    for (int t = 0; t < ntiles; t++) {
        if (t + 1 < ntiles) stage(buf ^ 1, kb + (t + 1) * 64);  // prefetch in flight
        const char* Asb = smem + buf * 16384;
        const char* Bsb = smem + 32768 + buf * (BN * 128);
#pragma unroll
        for (int ks = 0; ks < 2; ks++) {
            bf16x8 af[4], bfr[FN];
#pragma unroll
            for (int mi = 0; mi < 4; mi++) {
                int r = wr * 64 + mi * 16 + l15;
                af[mi] = *(const bf16x8*)(Asb + r * 128 + ((((ks << 2) | l4) ^ (r & 7)) << 4));
            }
#pragma unroll
            for (int nj = 0; nj < FN; nj++) {
                int c = wc * (FN * 16) + nj * 16 + l15;
                bfr[nj] = *(const bf16x8*)(Bsb + c * 128 + ((((ks << 2) | l4) ^ (c & 7)) << 4));
            }
#pragma unroll
            for (int mi = 0; mi < 4; mi++)
#pragma unroll
                for (int nj = 0; nj < FN; nj++)
                    acc[mi][nj] = __builtin_amdgcn_mfma_f32_16x16x32_bf16(
                        af[mi], bfr[nj], acc[mi][nj], 0, 0, 0);
        }
        __syncthreads();
        buf ^= 1;
    }
}

// MODE 0: Cb = bf16(acc)                          (g3 / E precompute)
// MODE 1: Cb = bf16(tanh(acc+bias+t*bias2))       (G1 -> h1)
// MODE 2: h2=tanh(acc+bias)->Cb; Cb2=aux*(1-h2^2) (G2 -> h2,g2; aux=g3)
template<int MODE>
__global__ __launch_bounds__(256)
void mfma_gemm(const u16* __restrict__ A, int K,
               const u16* __restrict__ Bt, int N,
               u16* __restrict__ Cb,
               const float* __restrict__ bias, const float* __restrict__ bias2,
               float tval,
               const u16* __restrict__ auxb, u16* __restrict__ Cb2)
{
    __shared__ __align__(16) char smem[65536];
    const int m0 = blockIdx.y * 128, n0 = blockIdx.x * 128;
    f32x4 acc[4][4] = {};
    kloop<128>(A, Bt, K, m0, n0, 0, K / 64, smem, acc);

    const int tid = threadIdx.x, wv = tid >> 6, lane = tid & 63;
    const int l15 = lane & 15, l4 = lane >> 4;
    const int wr = wv >> 1, wc = wv & 1;
    float* ep = (float*)smem;               // [128][34]
    const int erow = tid >> 1, ehalf = tid & 1;
    const int gm = m0 + erow;
#pragma unroll
    for (int c = 0; c < 4; c++) {
        __syncthreads();
        if (wc == (c >> 1)) {
            int njb = (c & 1) * 2;
#pragma unroll
            for (int mi = 0; mi < 4; mi++)
#pragma unroll
                for (int jj = 0; jj < 2; jj++)
#pragma unroll
                    for (int r = 0; r < 4; r++) {
                        int row = wr * 64 + mi * 16 + l4 * 4 + r;
                        ep[row * 34 + jj * 16 + l15] = acc[mi][njb + jj][r];
                    }
        }
        __syncthreads();
        float v[16];
#pragma unroll
        for (int j = 0; j < 16; j++) v[j] = ep[erow * 34 + ehalf * 16 + j];
        const int kbase = n0 + c * 32 + ehalf * 16;
        const int gsb = (n0 >> 3) + c * 4 + ehalf * 2;
        const size_t idxA = swz_slot(gm, gsb, N);
        const size_t idxB = swz_slot(gm, gsb + 1, N);

        if constexpr (MODE == 0) {
            union { bf16x8 v8; u16 u[8]; } pa, pb;
#pragma unroll
            for (int j = 0; j < 8; j++) { pa.u[j] = f2bf(v[j]); pb.u[j] = f2bf(v[j + 8]); }
            *(bf16x8*)(Cb + idxA) = pa.v8;
            *(bf16x8*)(Cb + idxB) = pb.v8;
        } else if constexpr (MODE == 1) {
            union { bf16x8 v8; u16 u[8]; } pa, pb;
#pragma unroll
            for (int j = 0; j < 8; j++) {
                pa.u[j] = f2bf(tanh_fast(v[j] + bias[kbase + j] + tval * bias2[kbase + j]));
                pb.u[j] = f2bf(tanh_fast(v[j + 8] + bias[kbase + 8 + j] + tval * bias2[kbase + 8 + j]));
            }
            *(bf16x8*)(Cb + idxA) = pa.v8;
            *(bf16x8*)(Cb + idxB) = pb.v8;
        } else if constexpr (MODE == 2) {
            union { bf16x8 v8; u16 u[8]; } ha, hb, ga, gb;
            bf16x8 a0 = *(const bf16x8*)(auxb + idxA);
            bf16x8 a1 = *(const bf16x8*)(auxb + idxB);
#pragma unroll
            for (int j = 0; j < 8; j++) {
                float h0 = tanh_fast(v[j] + bias[kbase + j]);
                float h1v = tanh_fast(v[j + 8] + bias[kbase + 8 + j]);
                ha.u[j] = f2bf(h0);
                hb.u[j] = f2bf(h1v);
                ga.u[j] = f2bf(bf2f((u16)a0[j]) * (1.f - h0 * h0));
                gb.u[j] = f2bf(bf2f((u16)a1[j]) * (1.f - h1v * h1v));
            }
            *(bf16x8*)(Cb  + idxA) = ha.v8;
            *(bf16x8*)(Cb  + idxB) = hb.v8;
            *(bf16x8*)(Cb2 + idxA) = ga.v8;
            *(bf16x8*)(Cb2 + idxB) = gb.v8;
        }
    }
}

// Fused G5(+trace) and G3: blockIdx.x<8 -> trace partials; else split-K dx partials.
// Concurrent execution shortens the serial critical path (both depend only on G2).
__global__ __launch_bounds__(256)
void fused_g5g3(const u16* __restrict__ g2, const u16* __restrict__ w2,
                const u16* __restrict__ h2, const u16* __restrict__ w3t,
                const u16* __restrict__ h1b, const u16* __restrict__ Eb,
                float* __restrict__ trp, float* __restrict__ part3)
{
    __shared__ __align__(16) char smem[65536];
    const int m0 = blockIdx.y * 128;
    const int tid = threadIdx.x, wv = tid >> 6, lane = tid & 63;
    const int l15 = lane & 15, l4 = lane >> 4;
    const int wr = wv >> 1, wc = wv & 1;

    if (blockIdx.x < 8) {
        // ---- G5 + trace: tr_partial = rowsum((g2@W2^T)*(1-h1^2)*E) over 128 cols ----
        const int n0 = blockIdx.x * 128;
        f32x4 acc[4][4] = {};
        kloop<128>(g2, w2, HID, m0, n0, 0, HID / 64, smem, acc);

        float* ep  = (float*)smem;
        float* red = (float*)(smem + 17408);
        const int erow = tid >> 1, ehalf = tid & 1;
        const int gm = m0 + erow;
        float tsum = 0.f;
#pragma unroll
        for (int c = 0; c < 4; c++) {
            __syncthreads();
            if (wc == (c >> 1)) {
                int njb = (c & 1) * 2;
#pragma unroll
                for (int mi = 0; mi < 4; mi++)
#pragma unroll
                    for (int jj = 0; jj < 2; jj++)
#pragma unroll
                        for (int r = 0; r < 4; r++) {
                            int row = wr * 64 + mi * 16 + l4 * 4 + r;
                            ep[row * 34 + jj * 16 + l15] = acc[mi][njb + jj][r];
                        }
            }
            __syncthreads();
            float v[16];
#pragma unroll
            for (int j = 0; j < 16; j++) v[j] = ep[erow * 34 + ehalf * 16 + j];
            const int gsb = (n0 >> 3) + c * 4 + ehalf * 2;
            const size_t idxA = swz_slot(gm, gsb, HID);
            const size_t idxB = swz_slot(gm, gsb + 1, HID);
            bf16x8 a0 = *(const bf16x8*)(h1b + idxA);
            bf16x8 a1 = *(const bf16x8*)(h1b + idxB);
            bf16x8 e0 = *(const bf16x8*)(Eb + idxA);
            bf16x8 e1 = *(const bf16x8*)(Eb + idxB);
#pragma unroll
            for (int j = 0; j < 8; j++) {
                float h0 = bf2f((u16)a0[j]), h1v = bf2f((u16)a1[j]);
                tsum += v[j]     * (1.f - h0 * h0)  * bf2f((u16)e0[j]);
                tsum += v[j + 8] * (1.f - h1v * h1v) * bf2f((u16)e1[j]);
            }
        }
        red[erow * 2 + ehalf] = tsum;
        __syncthreads();
        if (tid < 128)
            trp[(size_t)blockIdx.x * BATCH + m0 + tid] = red[tid * 2] + red[tid * 2 + 1];
    } else {
        // ---- G3 split-K: part3[kc] = h2[:, kc-chunk] @ W3[kc-chunk, :] ----
        const int kc = blockIdx.x - 8;
        f32x4 acc[4][2] = {};
        kloop<64>(h2, w3t, HID, m0, 0, kc * (HID / SPLITK), (HID / SPLITK) / 64, smem, acc);
#pragma unroll
        for (int mi = 0; mi < 4; mi++)
#pragma unroll
            for (int nj = 0; nj < 2; nj++)
#pragma unroll
                for (int r = 0; r < 4; r++) {
                    int gm2 = m0 + wr * 64 + mi * 16 + l4 * 4 + r;
                    int gn = wc * 32 + nj * 16 + l15;
                    part3[(size_t)kc * (BATCH * 64) + (size_t)gm2 * 64 + gn] = acc[mi][nj][r];
                }
    }
}

__global__ void init_state(const float* __restrict__ x,
                           float* __restrict__ yx, u16* __restrict__ xin_bf,
                           float* __restrict__ yld)
{
    int i = blockIdx.x * 256 + threadIdx.x;
    if (i < BATCH * FEAT) {
        float v = x[i];
        yx[i] = v;
        xin_bf[swz_off(i >> 6, i & 63, 64)] = f2bf(v);
    }
    if (i < BATCH) yld[i] = 0.f;
}

__global__ void cast_bf(const float* __restrict__ in, u16* __restrict__ out,
                        int n, int W)
{
    int i = blockIdx.x * 256 + threadIdx.x;
    if (i < n) out[swz_off(i / W, i % W, W)] = f2bf(in[i]);
}

// in [R][C] fp32 -> out [C][R] bf16 swizzled
__global__ void transpose_cast(const float* __restrict__ in, u16* __restrict__ out,
                               int R, int C)
{
    __shared__ float t[32][33];
    int bx = blockIdx.x * 32, by = blockIdx.y * 32;
    int tx = threadIdx.x, ty = threadIdx.y;  // block (32,8)
    for (int i = 0; i < 32; i += 8)
        t[ty + i][tx] = in[(size_t)(by + ty + i) * C + bx + tx];
    __syncthreads();
    for (int i = 0; i < 32; i += 8)
        out[swz_off(bx + ty + i, by + tx, R)] = f2bf(t[tx][ty + i]);
}

__global__ void rk4_combine(const float* __restrict__ part3, const float* __restrict__ b3,
                            const float* __restrict__ trpart,
                            float* __restrict__ yx, float* __restrict__ yld,
                            float* __restrict__ accx, float* __restrict__ accld,
                            float* __restrict__ ytmp, u16* __restrict__ xin_bf,
                            float* __restrict__ outp,
                            float wacc, float wtmp, int first, int fin, int last,
                            float h6)
{
    int i = blockIdx.x * 256 + threadIdx.x;
    if (i < BATCH * FEAT) {
        int f = i & 63;
        float d = b3[f];
#pragma unroll
        for (int kc = 0; kc < SPLITK; kc++) d += part3[(size_t)kc * (BATCH * 64) + i];
        float a = (first ? 0.f : accx[i]) + wacc * d;
        accx[i] = a;
        float nx;
        if (fin) { nx = yx[i] + h6 * a; yx[i] = nx; }
        else     { nx = yx[i] + wtmp * d; ytmp[i] = nx; }
        if (last) outp[i] = nx;
        else      xin_bf[swz_off(i >> 6, f, 64)] = f2bf(nx);
    } else if (i < BATCH * FEAT + BATCH) {
        int m = i - BATCH * FEAT;
        float d = 0.f;
#pragma unroll
        for (int nb = 0; nb < 8; nb++) d += trpart[nb * BATCH + m];
        d = -d;
        float a = (first ? 0.f : accld[m]) + wacc * d;
        accld[m] = a;
        if (fin) {
            float nl = yld[m] + h6 * a;
            yld[m] = nl;
            if (last) outp[BATCH * FEAT + m] = nl;
        }
    }
}

extern "C" void kernel_launch(void* const* d_in, const int* in_sizes, int n_in,
                              void* d_out, int out_size, void* d_ws, size_t ws_size,
                              hipStream_t stream)
{
    const float* x   = (const float*)d_in[0];
    const float* W1  = (const float*)d_in[1];
    const float* b1  = (const float*)d_in[2];
    const float* W2  = (const float*)d_in[3];
    const float* b2  = (const float*)d_in[4];
    const float* W3  = (const float*)d_in[5];
    const float* b3  = (const float*)d_in[6];
    const float* eps = (const float*)d_in[7];
    float* out = (float*)d_out;

    char* ws = (char*)d_ws;
    size_t o = 0;
    auto alloc = [&](size_t bytes) { char* p = ws + o; o += (bytes + 255) & ~(size_t)255; return p; };

    float* yx     = (float*)alloc((size_t)BATCH * FEAT * 4);
    float* yld    = (float*)alloc(BATCH * 4);
    float* ytmp   = (float*)alloc((size_t)BATCH * FEAT * 4);
    float* accx   = (float*)alloc((size_t)BATCH * FEAT * 4);
    float* accld  = (float*)alloc(BATCH * 4);
    float* part3  = (float*)alloc((size_t)SPLITK * BATCH * FEAT * 4);
    float* trpart = (float*)alloc((size_t)8 * BATCH * 4);
    u16* xin_bf   = (u16*)alloc((size_t)BATCH * FEAT * 2);
    u16* h1       = (u16*)alloc((size_t)BATCH * HID * 2);
    u16* h2       = (u16*)alloc((size_t)BATCH * HID * 2);
    u16* g2       = (u16*)alloc((size_t)BATCH * HID * 2);
    u16* g3       = (u16*)alloc((size_t)BATCH * HID * 2);
    u16* E_bf     = (u16*)alloc((size_t)BATCH * HID * 2);
    u16* eps_bf   = (u16*)alloc((size_t)BATCH * FEAT * 2);
    u16* w1tb     = (u16*)alloc((size_t)HID * FEAT * 2);   // [1024][64] = W1[:64]^T
    u16* w2t_bf   = (u16*)alloc((size_t)HID * HID * 2);    // W2^T
    u16* w2_bf    = (u16*)alloc((size_t)HID * HID * 2);    // W2
    u16* w3t_bf   = (u16*)alloc((size_t)FEAT * HID * 2);   // [64][1024] = W3^T
    u16* w3_bf    = (u16*)alloc((size_t)HID * FEAT * 2);   // W3

    const dim3 blk(256);
    const dim3 gBig(HID / 128, BATCH / 128);        // (8, 64)
    const dim3 gFused(8 + SPLITK, BATCH / 128);     // (12, 64)
    const int combN = (BATCH * FEAT + BATCH + 255) / 256;

    // ---- setup (every call; deterministic) ----
    init_state<<<dim3((BATCH * FEAT + 255) / 256), blk, 0, stream>>>(x, yx, xin_bf, yld);
    cast_bf<<<dim3((HID * HID + 255) / 256), blk, 0, stream>>>(W2, w2_bf, HID * HID, HID);
    cast_bf<<<dim3((HID * FEAT + 255) / 256), blk, 0, stream>>>(W3, w3_bf, HID * FEAT, FEAT);
    cast_bf<<<dim3((BATCH * FEAT + 255) / 256), blk, 0, stream>>>(eps, eps_bf, BATCH * FEAT, FEAT);
    transpose_cast<<<dim3(HID / 32, HID / 32), dim3(32, 8), 0, stream>>>(W2, w2t_bf, HID, HID);
    transpose_cast<<<dim3(HID / 32, FEAT / 32), dim3(32, 8), 0, stream>>>(W1, w1tb, FEAT, HID);
    transpose_cast<<<dim3(FEAT / 32, HID / 32), dim3(32, 8), 0, stream>>>(W3, w3t_bf, HID, FEAT);
    // g3 = eps @ W3^T
    mfma_gemm<0><<<gBig, blk, 0, stream>>>(eps_bf, FEAT, w3_bf, HID,
                                           g3, nullptr, nullptr, 0.f, nullptr, nullptr);
    // E = eps @ W1[:64]
    mfma_gemm<0><<<gBig, blk, 0, stream>>>(eps_bf, FEAT, w1tb, HID,
                                           E_bf, nullptr, nullptr, 0.f, nullptr, nullptr);

    const float h = 1.0f / NSTEPS;
    const float cs[4] = {0.f, 0.5f, 0.5f, 1.f};

    for (int s = 0; s < NSTEPS; s++) {
        float t0 = s * h;
        for (int st = 0; st < 4; st++) {
            float ts = t0 + cs[st] * h;
            // G1: h1 = tanh(xin @ W1[:64] + t*W1[64] + b1)
            mfma_gemm<1><<<gBig, blk, 0, stream>>>(xin_bf, FEAT, w1tb, HID,
                                                   h1, b1, W1 + (size_t)FEAT * HID, ts,
                                                   nullptr, nullptr);
            // G2: h2 = tanh(h1 @ W2 + b2); g2 = g3*(1-h2^2)
            mfma_gemm<2><<<gBig, blk, 0, stream>>>(h1, HID, w2t_bf, HID,
                                                   h2, b2, nullptr, 0.f,
                                                   g3, g2);
            // G5+trace (blocks 0..7) || G3 split-K (blocks 8..11), concurrent
            fused_g5g3<<<gFused, blk, 0, stream>>>(g2, w2_bf, h2, w3t_bf,
                                                   h1, E_bf, trpart, part3);
            float wacc = (st == 1 || st == 2) ? 2.f : 1.f;
            float wtmp = (st == 0 || st == 1) ? h * 0.5f : h;
            rk4_combine<<<dim3(combN), blk, 0, stream>>>(part3, b3, trpart,
                                                         yx, yld, accx, accld,
                                                         ytmp, xin_bf, out,
                                                         wacc, wtmp,
                                                         (st == 0) ? 1 : 0,
                                                         (st == 3) ? 1 : 0,
                                                         (s == NSTEPS - 1 && st == 3) ? 1 : 0,
                                                         h / 6.f);
        }
    }
}